// Round 7
// baseline (27529.388 us; speedup 1.0000x reference)
//
#include <hip/hip_runtime.h>

#define SEQ  8192
#define NT   2048
#define NBLK 256
#define NTHR 512
#define LOG2E 1.4426950408889634f
#define LN2   0.6931471805599453f

#define STORE_AG(p, v) __hip_atomic_store((p), (v), __ATOMIC_RELAXED, __HIP_MEMORY_SCOPE_AGENT)

typedef unsigned int u32x4 __attribute__((ext_vector_type(4)));

// Device-coherent 16B load (bypasses L1/L2). Each dword inside is individually
// tagged, so 16B-level tearing is harmless.
__device__ __forceinline__ u32x4 poll_load16(const unsigned int* p) {
    u32x4 r;
    asm volatile("global_load_dwordx4 %0, %1, off sc0 sc1\n\t"
                 "s_waitcnt vmcnt(0)"
                 : "=v"(r) : "v"(p) : "memory");
    return r;
}

// Packed state: word i of buffer t&1 = (tag<<16) | bf16(z[i]). One relaxed
// dword store publishes tag+data atomically; no flags, no fences.
__device__ __align__(16) unsigned int g_z[2][NT];
__device__ float g_gold;

__device__ __forceinline__ unsigned int f32_to_bf16(float f) {
    unsigned int u = __float_as_uint(f);
    return (u + 0x7FFFu + ((u >> 16) & 1u)) >> 16;  // RNE
}

// ---- init: z0 = exp(tstart + feats[0]) tagged 0; other buffer invalidated ----
__global__ void crf_init(const float* __restrict__ feats,
                         const float* __restrict__ tstart) {
    int i = blockIdx.x * blockDim.x + threadIdx.x;
    if (i < NT) {
        float z0 = __builtin_exp2f((tstart[i] + feats[i]) * LOG2E);
        g_z[0][i] = f32_to_bf16(z0);   // tag 0
        g_z[1][i] = 0xFFFF0000u;       // tag never matched (t <= 8191)
    }
}

// ---- gold path score (verified rounds 1-6) ----
__global__ void crf_gold(const float* __restrict__ feats,
                         const float* __restrict__ trans,
                         const float* __restrict__ tstart,
                         const float* __restrict__ tstop,
                         const int*   __restrict__ tags) {
    __shared__ float part[16];
    int tid = threadIdx.x;
    float acc = 0.f;
    for (int t = 1 + tid; t < SEQ; t += 1024) {
        int cur = tags[t], prev = tags[t - 1];
        acc += trans[(size_t)cur * NT + prev] + feats[(size_t)t * NT + cur];
    }
    #pragma unroll
    for (int m = 1; m < 64; m <<= 1) acc += __shfl_xor(acc, m, 64);
    if ((tid & 63) == 0) part[tid >> 6] = acc;
    __syncthreads();
    if (tid == 0) {
        float S = 0.f;
        #pragma unroll
        for (int w = 0; w < 16; ++w) S += part[w];
        int t0 = tags[0], tl = tags[SEQ - 1];
        g_gold = S + tstart[t0] + feats[t0] + tstop[tl];
    }
}

// ---- main recurrence: 256 blocks x 512 threads, TRANSPOSED decomposition ----
// Thread tid polls z-words 4*tid..4*tid+3 and FMAs them directly against
// E[r][q] = exp(T[8b+r][4*tid+q]) for all 8 block rows (no w-unpack, no LDS
// staging, no barrier A). 8 butterfly reduces -> lane0 writes 8 partials to
// tiny parity-buffered LDS -> ONE barrier -> wave 0 cross-wave reduce (3
// shfl) -> lanes 0-7 scale & publish one coalesced 8-dword store.
// Safety: all polls precede the barrier, all stores follow it => published
// tag t implies that block fully consumed t-1 => t-2 slots globally dead.
// LDS parity: a wave cannot pass barrier t+1 before wave 0 arrives there,
// so waves are within 1 step of wave 0 => 2 buffers suffice.
__global__ void __launch_bounds__(NTHR)
crf_main(const float* __restrict__ feats, const float* __restrict__ trans,
         const float* __restrict__ tstop, float* __restrict__ out) {
    const int b   = blockIdx.x;
    const int tid = threadIdx.x;
    const int wv  = tid >> 6;
    const int l   = tid & 63;

    __shared__ float part[2][64];   // [parity][src_wave*8 + row]

    // E[r][q] = exp(T[8b+r][4*tid+q]), r<8 block rows, q<4 polled cols.
    float E[8][4];
    {
        const float* tb = trans + (size_t)(b * 8) * NT + 4 * tid;
        #pragma unroll
        for (int r = 0; r < 8; ++r) {
            #pragma unroll
            for (int q = 0; q < 4; ++q)
                E[r][q] = __builtin_exp2f(tb[(size_t)r * NT + q] * LOG2E);
        }
    }

    // wave 0, lane r<8: exp(feat_t[8b+r]) for step t=1, kept one step ahead
    float fexp = 0.f;
    if (wv == 0 && l < 8)
        fexp = __builtin_exp2f(feats[(size_t)NT + b * 8 + l] * LOG2E);
    int esum = 0;   // only tid 0's copy is consumed

    for (int t = 1; t < SEQ; ++t) {
        const int par = (t - 1) & 1;
        const unsigned int need = (unsigned int)(t - 1);

        // ---- one-shot poll of own 4 tagged words ----
        u32x4 v;
        do { v = poll_load16(g_z[par] + 4 * tid); }
        while ((v.x >> 16) != need || (v.y >> 16) != need ||
               (v.z >> 16) != need || (v.w >> 16) != need);

        const float w0 = __uint_as_float(v.x << 16);
        const float w1 = __uint_as_float(v.y << 16);
        const float w2 = __uint_as_float(v.z << 16);
        const float w3 = __uint_as_float(v.w << 16);

        // ---- 8 row-partials in registers (32 FMA, no LDS) ----
        float p[8];
        #pragma unroll
        for (int r = 0; r < 8; ++r) {
            float a = E[r][0] * w0;
            a = fmaf(E[r][1], w1, a);
            a = fmaf(E[r][2], w2, a);
            a = fmaf(E[r][3], w3, a);
            p[r] = a;
        }
        // ---- butterfly reduce each partial across the wave (ILP 8) ----
        #pragma unroll
        for (int m = 1; m < 64; m <<= 1) {
            #pragma unroll
            for (int r = 0; r < 8; ++r) p[r] += __shfl_xor(p[r], m, 64);
        }
        if (l == 0) {
            #pragma unroll
            for (int r = 0; r < 8; ++r) part[par][wv * 8 + r] = p[r];
        }

        // ---- wave 0: scale from word 0's bf16 exponent; prefetch next fexp ----
        float scale = 0.f, fexpnext = 0.f;
        if (wv == 0) {
            unsigned int w0bits = __shfl(v.x, 0, 64);   // word 0 (tid 0's v.x)
            int e = (int)((w0bits >> 7) & 0xFFu) - 127;
            scale = __uint_as_float((unsigned int)(127 - e) << 23);
            if (tid == 0) esum += e;
            if (l < 8 && t + 1 < SEQ)
                fexpnext = __builtin_exp2f(feats[(size_t)(t + 1) * NT + b * 8 + l] * LOG2E);
        }
        __syncthreads();   // partials ready; all polls for t-1 complete

        if (wv == 0) {
            float val = part[par][l];          // l = src_wave*8 + row
            #pragma unroll
            for (int m = 8; m < 64; m <<= 1) val += __shfl_xor(val, m, 64);
            if (l < 8) {                       // row l total
                float znew = val * scale * fexp;
                STORE_AG(&g_z[t & 1][b * 8 + l],
                         ((unsigned int)t << 16) | f32_to_bf16(znew));
            }
            fexp = fexpnext;
        }
    }

    // ---- final: lse of z_{SEQ-1} with stop transitions, minus gold ----
    if (b == 0) {
        __shared__ float red[8];
        const unsigned int need = SEQ - 1;
        u32x4 v;
        do { v = poll_load16(g_z[(SEQ - 1) & 1] + 4 * tid); }
        while ((v.x >> 16) != need || (v.y >> 16) != need ||
               (v.z >> 16) != need || (v.w >> 16) != need);

        float acc =
            __uint_as_float(v.x << 16) * __builtin_exp2f(tstop[4 * tid + 0] * LOG2E) +
            __uint_as_float(v.y << 16) * __builtin_exp2f(tstop[4 * tid + 1] * LOG2E) +
            __uint_as_float(v.z << 16) * __builtin_exp2f(tstop[4 * tid + 2] * LOG2E) +
            __uint_as_float(v.w << 16) * __builtin_exp2f(tstop[4 * tid + 3] * LOG2E);
        #pragma unroll
        for (int m = 1; m < 64; m <<= 1) acc += __shfl_xor(acc, m, 64);
        if (l == 0) red[wv] = acc;
        __syncthreads();
        if (tid == 0) {
            float S = 0.f;
            #pragma unroll
            for (int w = 0; w < 8; ++w) S += red[w];
            float fwd = (__builtin_log2f(S) + (float)esum) * LN2;
            out[0] = fwd - g_gold;
        }
    }
}

extern "C" void kernel_launch(void* const* d_in, const int* in_sizes, int n_in,
                              void* d_out, int out_size, void* d_ws, size_t ws_size,
                              hipStream_t stream) {
    const float* feats  = (const float*)d_in[0];
    const float* trans  = (const float*)d_in[1];
    const float* tstart = (const float*)d_in[2];
    const float* tstop  = (const float*)d_in[3];
    const int*   tags   = (const int*)d_in[4];
    float* out = (float*)d_out;

    hipLaunchKernelGGL(crf_init, dim3(2), dim3(1024), 0, stream, feats, tstart);
    hipLaunchKernelGGL(crf_gold, dim3(1), dim3(1024), 0, stream,
                       feats, trans, tstart, tstop, tags);
    hipLaunchKernelGGL(crf_main, dim3(NBLK), dim3(NTHR), 0, stream,
                       feats, trans, tstop, out);
}

// Round 8
// 21040.565 us; speedup vs baseline: 1.3084x; 1.3084x over previous
//
#include <hip/hip_runtime.h>

#define SEQ  8192
#define NT   2048
#define NBLK 256
#define NTHR 512
#define LOG2E 1.4426950408889634f
#define LN2   0.6931471805599453f

#define STORE_AG(p, v) __hip_atomic_store((p), (v), __ATOMIC_RELAXED, __HIP_MEMORY_SCOPE_AGENT)

typedef unsigned int u32x4 __attribute__((ext_vector_type(4)));
typedef float f32x4 __attribute__((ext_vector_type(4)));

// Device-coherent 16B load (bypasses L1/L2 -> served from LLC). Each dword
// inside is individually tagged, so 16B-level tearing is harmless.
__device__ __forceinline__ u32x4 poll_load16(const unsigned int* p) {
    u32x4 r;
    asm volatile("global_load_dwordx4 %0, %1, off sc0 sc1\n\t"
                 "s_waitcnt vmcnt(0)"
                 : "=v"(r) : "v"(p) : "memory");
    return r;
}

// Packed state: word i of buffer t&1 = (tag<<16) | bf16(z[i]). One relaxed
// dword store publishes tag+data atomically; no flags, no fences.
__device__ __align__(16) unsigned int g_z[2][NT];
__device__ float g_gold;

__device__ __forceinline__ unsigned int f32_to_bf16(float f) {
    unsigned int u = __float_as_uint(f);
    return (u + 0x7FFFu + ((u >> 16) & 1u)) >> 16;  // RNE
}

// ---- init: z0 = exp(tstart + feats[0]) tagged 0; other buffer invalidated ----
__global__ void crf_init(const float* __restrict__ feats,
                         const float* __restrict__ tstart) {
    int i = blockIdx.x * blockDim.x + threadIdx.x;
    if (i < NT) {
        float z0 = __builtin_exp2f((tstart[i] + feats[i]) * LOG2E);
        g_z[0][i] = f32_to_bf16(z0);   // tag 0
        g_z[1][i] = 0xFFFF0000u;       // tag never matched (t <= 8191)
    }
}

// ---- gold path score (verified rounds 1-7) ----
__global__ void crf_gold(const float* __restrict__ feats,
                         const float* __restrict__ trans,
                         const float* __restrict__ tstart,
                         const float* __restrict__ tstop,
                         const int*   __restrict__ tags) {
    __shared__ float part[16];
    int tid = threadIdx.x;
    float acc = 0.f;
    for (int t = 1 + tid; t < SEQ; t += 1024) {
        int cur = tags[t], prev = tags[t - 1];
        acc += trans[(size_t)cur * NT + prev] + feats[(size_t)t * NT + cur];
    }
    #pragma unroll
    for (int m = 1; m < 64; m <<= 1) acc += __shfl_xor(acc, m, 64);
    if ((tid & 63) == 0) part[tid >> 6] = acc;
    __syncthreads();
    if (tid == 0) {
        float S = 0.f;
        #pragma unroll
        for (int w = 0; w < 16; ++w) S += part[w];
        int t0 = tags[0], tl = tags[SEQ - 1];
        g_gold = S + tstart[t0] + feats[t0] + tstop[tl];
    }
}

// ---- main recurrence: 256 blocks x 512 threads (R6 structure) ----
// Linear domain: z_t = (E z_{t-1}) * exp(feat_t) * 2^-e, e = exponent(z[0]),
// exact power-of-2 shift, identical in every block, integer-accumulated.
// Change vs R6: the dot reads w via ds_read_b128 (lane l owns contiguous
// 4-col chunks at 4l + 256u) -> 8 wide LDS reads/wave instead of 32 narrow,
// halving DS-pipe time per CU per step. E regs remapped to match.
// Safety: all polls precede barrier A, all stores follow barrier B => tag t
// published implies t-1 fully consumed by that block => t-2 slots dead.
__global__ void __launch_bounds__(NTHR)
crf_main(const float* __restrict__ feats, const float* __restrict__ trans,
         const float* __restrict__ tstop, float* __restrict__ out) {
    const int b   = blockIdx.x;
    const int tid = threadIdx.x;
    const int wid = tid >> 6;
    const int l   = tid & 63;
    const int j   = b * 8 + wid;

    __shared__ __align__(16) float w_lds[2][NT];   // parity double-buffer
    __shared__ float s_scale[2];
    __shared__ unsigned int pk[8];     // packed per-wave results
    __shared__ float red[8];

    // E[u][q] = exp(T[j][4l + 256u + q]) in [1, e); 32 VGPRs.
    // Per-u global reads are fully coalesced across the wave (256 consecutive).
    float E[8][4];
    {
        const float* trow = trans + (size_t)j * NT + 4 * l;
        #pragma unroll
        for (int u = 0; u < 8; ++u) {
            #pragma unroll
            for (int q = 0; q < 4; ++q)
                E[u][q] = __builtin_exp2f(trow[256 * u + q] * LOG2E);
        }
    }

    // exp(feat) for step 1, precomputed off the critical path
    float fexp = __builtin_exp2f(feats[(size_t)NT + j] * LOG2E);
    int esum = 0;   // only block 0 / tid 0's copy is consumed

    for (int t = 1; t < SEQ; ++t) {
        const int par = (t - 1) & 1;
        const unsigned int need = (unsigned int)(t - 1);
        const unsigned int* buf = g_z[par] + 4 * tid;

        // ---- one-shot poll: 4 tagged words per thread, 1 instr per retry ----
        u32x4 v;
        do { v = poll_load16(buf); }
        while ((v.x >> 16) != need || (v.y >> 16) != need ||
               (v.z >> 16) != need || (v.w >> 16) != need);

        // unpack bf16 -> f32 into LDS as ONE 16B store
        {
            f32x4 wq;
            wq.x = __uint_as_float(v.x << 16);
            wq.y = __uint_as_float(v.y << 16);
            wq.z = __uint_as_float(v.z << 16);
            wq.w = __uint_as_float(v.w << 16);
            *(f32x4*)&w_lds[par][4 * tid] = wq;
        }

        if (tid == 0) {
            int e = (int)((v.x >> 7) & 0xFFu) - 127;   // bf16 exponent of word 0
            s_scale[par] = __uint_as_float((unsigned int)(127 - e) << 23);
            esum += e;
        }
        // prefetch next feat + exp (off critical path; wave-uniform addr)
        float fexpnext = (t + 1 < SEQ)
            ? __builtin_exp2f(feats[(size_t)(t + 1) * NT + j] * LOG2E) : 0.f;
        __syncthreads();   // A: w_lds + s_scale ready

        // ---- dot via 8 wide LDS reads: acc = sum_u E[u][:] . w[4l+256u .. +3] ----
        float acc = 0.f;
        #pragma unroll
        for (int u = 0; u < 8; ++u) {
            f32x4 wq = *(const f32x4*)&w_lds[par][4 * l + 256 * u];
            acc = fmaf(E[u][0], wq.x, acc);
            acc = fmaf(E[u][1], wq.y, acc);
            acc = fmaf(E[u][2], wq.z, acc);
            acc = fmaf(E[u][3], wq.w, acc);
        }
        #pragma unroll
        for (int m = 1; m < 64; m <<= 1) acc += __shfl_xor(acc, m, 64);

        if (l == 0) {
            float znew = acc * s_scale[par] * fexp;
            pk[wid] = ((unsigned int)t << 16) | f32_to_bf16(znew);
        }
        fexp = fexpnext;
        __syncthreads();   // B: all 8 results gathered

        // ---- ONE coalesced publication: lanes 0-7, 8 contiguous dwords ----
        if (tid < 8) STORE_AG(&g_z[t & 1][b * 8 + tid], pk[tid]);
    }

    // ---- final: lse of z_{SEQ-1} with stop transitions, minus gold ----
    if (b == 0) {
        const unsigned int need = SEQ - 1;
        const unsigned int* buf = g_z[(SEQ - 1) & 1] + 4 * tid;
        u32x4 v;
        do { v = poll_load16(buf); }
        while ((v.x >> 16) != need || (v.y >> 16) != need ||
               (v.z >> 16) != need || (v.w >> 16) != need);

        float acc =
            __uint_as_float(v.x << 16) * __builtin_exp2f(tstop[4 * tid + 0] * LOG2E) +
            __uint_as_float(v.y << 16) * __builtin_exp2f(tstop[4 * tid + 1] * LOG2E) +
            __uint_as_float(v.z << 16) * __builtin_exp2f(tstop[4 * tid + 2] * LOG2E) +
            __uint_as_float(v.w << 16) * __builtin_exp2f(tstop[4 * tid + 3] * LOG2E);
        #pragma unroll
        for (int m = 1; m < 64; m <<= 1) acc += __shfl_xor(acc, m, 64);
        if (l == 0) red[wid] = acc;
        __syncthreads();
        if (tid == 0) {
            float S = 0.f;
            #pragma unroll
            for (int w = 0; w < 8; ++w) S += red[w];
            float fwd = (__builtin_log2f(S) + (float)esum) * LN2;
            out[0] = fwd - g_gold;
        }
    }
}

extern "C" void kernel_launch(void* const* d_in, const int* in_sizes, int n_in,
                              void* d_out, int out_size, void* d_ws, size_t ws_size,
                              hipStream_t stream) {
    const float* feats  = (const float*)d_in[0];
    const float* trans  = (const float*)d_in[1];
    const float* tstart = (const float*)d_in[2];
    const float* tstop  = (const float*)d_in[3];
    const int*   tags   = (const int*)d_in[4];
    float* out = (float*)d_out;

    hipLaunchKernelGGL(crf_init, dim3(2), dim3(1024), 0, stream, feats, tstart);
    hipLaunchKernelGGL(crf_gold, dim3(1), dim3(1024), 0, stream,
                       feats, trans, tstart, tstop, tags);
    hipLaunchKernelGGL(crf_main, dim3(NBLK), dim3(NTHR), 0, stream,
                       feats, trans, tstop, out);
}

// Round 9
// 18235.265 us; speedup vs baseline: 1.5097x; 1.1538x over previous
//
#include <hip/hip_runtime.h>

#define SEQ  8192
#define NT   2048
#define NBLK 128
#define NTHR 512
#define LOG2E 1.4426950408889634f
#define LN2   0.6931471805599453f

#define STORE_AG(p, v) __hip_atomic_store((p), (v), __ATOMIC_RELAXED, __HIP_MEMORY_SCOPE_AGENT)

typedef unsigned int u32x4 __attribute__((ext_vector_type(4)));
typedef float f32x4 __attribute__((ext_vector_type(4)));

// Device-coherent 16B load (bypasses L1/L2 -> served from LLC). Each dword
// inside is individually tagged, so 16B-level tearing is harmless.
__device__ __forceinline__ u32x4 poll_load16(const unsigned int* p) {
    u32x4 r;
    asm volatile("global_load_dwordx4 %0, %1, off sc0 sc1\n\t"
                 "s_waitcnt vmcnt(0)"
                 : "=v"(r) : "v"(p) : "memory");
    return r;
}

// Packed state: word i of buffer t&1 = (tag<<16) | bf16(z[i]). One relaxed
// dword store publishes tag+data atomically; no flags, no fences.
__device__ __align__(16) unsigned int g_z[2][NT];
__device__ float g_gold;

__device__ __forceinline__ unsigned int f32_to_bf16(float f) {
    unsigned int u = __float_as_uint(f);
    return (u + 0x7FFFu + ((u >> 16) & 1u)) >> 16;  // RNE
}

// ---- init: z0 = exp(tstart + feats[0]) tagged 0; other buffer invalidated ----
__global__ void crf_init(const float* __restrict__ feats,
                         const float* __restrict__ tstart) {
    int i = blockIdx.x * blockDim.x + threadIdx.x;
    if (i < NT) {
        float z0 = __builtin_exp2f((tstart[i] + feats[i]) * LOG2E);
        g_z[0][i] = f32_to_bf16(z0);   // tag 0
        g_z[1][i] = 0xFFFF0000u;       // tag never matched (t <= 8191)
    }
}

// ---- gold path score (verified rounds 1-8) ----
__global__ void crf_gold(const float* __restrict__ feats,
                         const float* __restrict__ trans,
                         const float* __restrict__ tstart,
                         const float* __restrict__ tstop,
                         const int*   __restrict__ tags) {
    __shared__ float part[16];
    int tid = threadIdx.x;
    float acc = 0.f;
    for (int t = 1 + tid; t < SEQ; t += 1024) {
        int cur = tags[t], prev = tags[t - 1];
        acc += trans[(size_t)cur * NT + prev] + feats[(size_t)t * NT + cur];
    }
    #pragma unroll
    for (int m = 1; m < 64; m <<= 1) acc += __shfl_xor(acc, m, 64);
    if ((tid & 63) == 0) part[tid >> 6] = acc;
    __syncthreads();
    if (tid == 0) {
        float S = 0.f;
        #pragma unroll
        for (int w = 0; w < 16; ++w) S += part[w];
        int t0 = tags[0], tl = tags[SEQ - 1];
        g_gold = S + tstart[t0] + feats[t0] + tstop[tl];
    }
}

// ---- main recurrence: 128 blocks x 512 threads, 2 rows per wave ----
// vs R8 (single change class): halve the exchange population. Each wave owns
// rows j0 = 16b + 2wv, j1 = j0 + 1. The ds_read_b128 of w is SHARED by both
// rows (only E differs, in registers), so DS-pipe time per CU is unchanged;
// cost is +32 FMA/lane and a second interleaved butterfly. Pollers halve
// (65K), publishers halve (128 x 64B contiguous), skew max over 128 blocks.
// Safety proof unchanged: all polls precede barrier A, all stores follow
// barrier B => published tag t implies t-1 fully consumed => t-2 slots dead.
__global__ void __launch_bounds__(NTHR)
crf_main(const float* __restrict__ feats, const float* __restrict__ trans,
         const float* __restrict__ tstop, float* __restrict__ out) {
    const int b   = blockIdx.x;
    const int tid = threadIdx.x;
    const int wid = tid >> 6;
    const int l   = tid & 63;
    const int j0  = b * 16 + wid * 2;   // wave's first row; second is j0+1

    __shared__ __align__(16) float w_lds[2][NT];   // parity double-buffer
    __shared__ float s_scale[2];
    __shared__ unsigned int pk[16];    // packed per-row results
    __shared__ float red[8];

    // E0/E1[u][q] = exp(T[j0/j0+1][4l + 256u + q]) in [1, e); 64 VGPRs.
    float E0[8][4], E1[8][4];
    {
        const float* tr0 = trans + (size_t)j0 * NT + 4 * l;
        const float* tr1 = tr0 + NT;
        #pragma unroll
        for (int u = 0; u < 8; ++u) {
            #pragma unroll
            for (int q = 0; q < 4; ++q) {
                E0[u][q] = __builtin_exp2f(tr0[256 * u + q] * LOG2E);
                E1[u][q] = __builtin_exp2f(tr1[256 * u + q] * LOG2E);
            }
        }
    }

    // lanes 0,1: exp(feat_t[j0+l]) for step 1, kept one step ahead
    float fexp = (l < 2)
        ? __builtin_exp2f(feats[(size_t)NT + j0 + l] * LOG2E) : 0.f;
    int esum = 0;   // only block 0 / tid 0's copy is consumed

    for (int t = 1; t < SEQ; ++t) {
        const int par = (t - 1) & 1;
        const unsigned int need = (unsigned int)(t - 1);
        const unsigned int* buf = g_z[par] + 4 * tid;

        // ---- one-shot poll: 4 tagged words per thread, 1 instr per retry ----
        u32x4 v;
        do { v = poll_load16(buf); }
        while ((v.x >> 16) != need || (v.y >> 16) != need ||
               (v.z >> 16) != need || (v.w >> 16) != need);

        // unpack bf16 -> f32 into LDS as ONE 16B store
        {
            f32x4 wq;
            wq.x = __uint_as_float(v.x << 16);
            wq.y = __uint_as_float(v.y << 16);
            wq.z = __uint_as_float(v.z << 16);
            wq.w = __uint_as_float(v.w << 16);
            *(f32x4*)&w_lds[par][4 * tid] = wq;
        }

        if (tid == 0) {
            int e = (int)((v.x >> 7) & 0xFFu) - 127;   // bf16 exponent of word 0
            s_scale[par] = __uint_as_float((unsigned int)(127 - e) << 23);
            esum += e;
        }
        // prefetch next feat + exp (off critical path; lanes 0,1 only)
        float fexpnext = (l < 2 && t + 1 < SEQ)
            ? __builtin_exp2f(feats[(size_t)(t + 1) * NT + j0 + l] * LOG2E) : 0.f;
        __syncthreads();   // A: w_lds + s_scale ready

        // ---- two dots sharing each ds_read_b128 of w ----
        float accA = 0.f, accB = 0.f;
        #pragma unroll
        for (int u = 0; u < 8; ++u) {
            f32x4 wq = *(const f32x4*)&w_lds[par][4 * l + 256 * u];
            accA = fmaf(E0[u][0], wq.x, accA);
            accB = fmaf(E1[u][0], wq.x, accB);
            accA = fmaf(E0[u][1], wq.y, accA);
            accB = fmaf(E1[u][1], wq.y, accB);
            accA = fmaf(E0[u][2], wq.z, accA);
            accB = fmaf(E1[u][2], wq.z, accB);
            accA = fmaf(E0[u][3], wq.w, accA);
            accB = fmaf(E1[u][3], wq.w, accB);
        }
        #pragma unroll
        for (int m = 1; m < 64; m <<= 1) {
            accA += __shfl_xor(accA, m, 64);
            accB += __shfl_xor(accB, m, 64);
        }

        if (l < 2) {   // lane 0 finalizes row j0, lane 1 row j0+1
            float tot = l ? accB : accA;
            float znew = tot * s_scale[par] * fexp;
            pk[wid * 2 + l] = ((unsigned int)t << 16) | f32_to_bf16(znew);
        }
        fexp = fexpnext;
        __syncthreads();   // B: all 16 results gathered

        // ---- ONE coalesced publication: lanes 0-15, 16 contiguous dwords ----
        if (tid < 16) STORE_AG(&g_z[t & 1][b * 16 + tid], pk[tid]);
    }

    // ---- final: lse of z_{SEQ-1} with stop transitions, minus gold ----
    if (b == 0) {
        const unsigned int need = SEQ - 1;
        const unsigned int* buf = g_z[(SEQ - 1) & 1] + 4 * tid;
        u32x4 v;
        do { v = poll_load16(buf); }
        while ((v.x >> 16) != need || (v.y >> 16) != need ||
               (v.z >> 16) != need || (v.w >> 16) != need);

        float acc =
            __uint_as_float(v.x << 16) * __builtin_exp2f(tstop[4 * tid + 0] * LOG2E) +
            __uint_as_float(v.y << 16) * __builtin_exp2f(tstop[4 * tid + 1] * LOG2E) +
            __uint_as_float(v.z << 16) * __builtin_exp2f(tstop[4 * tid + 2] * LOG2E) +
            __uint_as_float(v.w << 16) * __builtin_exp2f(tstop[4 * tid + 3] * LOG2E);
        #pragma unroll
        for (int m = 1; m < 64; m <<= 1) acc += __shfl_xor(acc, m, 64);
        if (l == 0) red[wid] = acc;
        __syncthreads();
        if (tid == 0) {
            float S = 0.f;
            #pragma unroll
            for (int w = 0; w < 8; ++w) S += red[w];
            float fwd = (__builtin_log2f(S) + (float)esum) * LN2;
            out[0] = fwd - g_gold;
        }
    }
}

extern "C" void kernel_launch(void* const* d_in, const int* in_sizes, int n_in,
                              void* d_out, int out_size, void* d_ws, size_t ws_size,
                              hipStream_t stream) {
    const float* feats  = (const float*)d_in[0];
    const float* trans  = (const float*)d_in[1];
    const float* tstart = (const float*)d_in[2];
    const float* tstop  = (const float*)d_in[3];
    const int*   tags   = (const int*)d_in[4];
    float* out = (float*)d_out;

    hipLaunchKernelGGL(crf_init, dim3(2), dim3(1024), 0, stream, feats, tstart);
    hipLaunchKernelGGL(crf_gold, dim3(1), dim3(1024), 0, stream,
                       feats, trans, tstart, tstop, tags);
    hipLaunchKernelGGL(crf_main, dim3(NBLK), dim3(NTHR), 0, stream,
                       feats, trans, tstop, out);
}